// Round 6
// baseline (148.374 us; speedup 1.0000x reference)
//
#include <hip/hip_runtime.h>

// Grouped_Soft_GSL_Block_PE fused kernel for MI355X (gfx950).
// B=8, IC2=128, N=2048, K=32, C=64, G=8, CPG=8, hidden=16.
// R6: 512 blocks, 256 thr / 4 waves; block owns 32 n, 8 iterations of
// (4 n)-tiles; wave wv owns n = nblk + 4*it + wv. Zero barriers in loop.
// Changes vs R5: __launch_bounds__(256,2) to force <=256 unified VGPR+AGPR
// (R4/R5 sat at ~264 -> 1 wave/SIMD); ~30 regs shaved to avoid spill:
// pb2v -> trQ float4 LDS table, cr[] copy removed (rel prefetch moved after
// use), pw1f compressed to uint2 pairs.

typedef __attribute__((ext_vector_type(8))) short bf16x8;
typedef __attribute__((ext_vector_type(4))) float f32x4;

#define EPS_BN 1e-5f

__device__ __forceinline__ unsigned pk2(float a, float b){
  unsigned ua = __float_as_uint(a) + 0x8000u;
  unsigned ub = __float_as_uint(b) + 0x8000u;
  return __builtin_amdgcn_perm(ub, ua, 0x07060302);
}
__device__ __forceinline__ short f2bf(float a){
  unsigned u = __float_as_uint(a);
  u += 0x7FFFu + ((u >> 16) & 1u);
  return (short)(u >> 16);
}
__device__ __forceinline__ bf16x8 mk8(float4 a, float4 b){
  union { bf16x8 v; unsigned u[4]; } t;
  t.u[0] = pk2(a.x, a.y); t.u[1] = pk2(a.z, a.w);
  t.u[2] = pk2(b.x, b.y); t.u[3] = pk2(b.z, b.w);
  return t.v;
}
__device__ __forceinline__ float lrelu(float v){ return fmaxf(v, 0.2f*v); }

// DPP row_ror reductions over the 16-lane row (l15 = k dimension)
template<int N>
__device__ __forceinline__ float ror16(float x){
  return __int_as_float(__builtin_amdgcn_mov_dpp(__float_as_int(x), 0x120+N, 0xF, 0xF, false));
}
__device__ __forceinline__ float rsum16(float v){
  v += ror16<1>(v); v += ror16<2>(v); v += ror16<4>(v); v += ror16<8>(v); return v;
}
__device__ __forceinline__ float rmax16(float v){
  v = fmaxf(v, ror16<1>(v)); v = fmaxf(v, ror16<2>(v));
  v = fmaxf(v, ror16<4>(v)); v = fmaxf(v, ror16<8>(v)); return v;
}

#define MFMA16(a,b,c) __builtin_amdgcn_mfma_f32_16x16x32_bf16((a),(b),(c),0,0,0)

__global__ __launch_bounds__(256, 2)
void gsl_fused(const float* __restrict__ x,       const float* __restrict__ rel_pos,
               const float* __restrict__ pos_w1,  const float* __restrict__ pos_g,
               const float* __restrict__ pos_bb,  const float* __restrict__ pos_m,
               const float* __restrict__ pos_v,   const float* __restrict__ pos_w2,
               const float* __restrict__ pos_b2,  const float* __restrict__ pe_w,
               const float* __restrict__ pe_b,    const float* __restrict__ trans_w,
               const float* __restrict__ tr_g,    const float* __restrict__ tr_bb,
               const float* __restrict__ tr_m,    const float* __restrict__ tr_v,
               const float* __restrict__ gate_w1, const float* __restrict__ ga_g,
               const float* __restrict__ ga_bb,   const float* __restrict__ ga_m,
               const float* __restrict__ ga_v,    const float* __restrict__ gate_w2,
               const float* __restrict__ gate_b2, const float* __restrict__ attn_w1,
               const float* __restrict__ at_g,    const float* __restrict__ at_bb,
               const float* __restrict__ at_m,    const float* __restrict__ at_v,
               const float* __restrict__ attn_w2, const float* __restrict__ attn_b2,
               float* __restrict__ out)
{
  // LDS map (73152 B, 2 blocks/CU):
  // [0,34816)      xbuf [128 cols][136] bf16; wave slice 8704B at wv*8704,
  //                aliased post-GEMM per wave: h1b [32][72] @0, gab [32][40] @4608
  // [34816,60928)  wmain [96][136] bf16 (trans 0..63, gate 64..79, attn 80..95)
  // [60928,71296)  wpos2 [72][72] bf16 (rows 0..63 pos_w2; 64..71 peW2 fold;
  //                A-frag junk reads of rows 72..79 land in tabs -> harmless)
  // [71296,73152)  tabs f32: trQ[256] (s,b,pos_b2,0 quads) p1T[128] gaT[32]
  //                atT[32] peBt[16]
  __shared__ __align__(16) char smem[73152];
  short* xbuf  = (short*)smem;
  short* wmain = (short*)(smem + 34816);
  short* wpos2 = (short*)(smem + 60928);
  float* trQ  = (float*)(smem + 71296);   // float4 per channel
  float* p1T  = (float*)(smem + 72320);   // (scale,bias) pairs
  float* gaT  = (float*)(smem + 72832);
  float* atT  = (float*)(smem + 72960);
  float* peBt = (float*)(smem + 73088);

  const int tid = threadIdx.x;
  const int wv  = tid >> 6;
  const int l   = tid & 63;
  const int l15 = l & 15, g4 = l >> 4;
  const int bid = blockIdx.x;
  const int b    = bid >> 6;
  const int nblk = (bid & 63) << 5;

  // ---- stage weights -> LDS bf16 ----
  if (tid < 192){
    int r = tid >> 1, c0 = (tid & 1) * 64;
    const float* src = (r < 64) ? (trans_w + r*128)
                     : (r < 80) ? (gate_w1 + (r-64)*128)
                                : (attn_w1 + (r-80)*128);
    src += c0;
    short* dst = wmain + r*136 + c0;
    #pragma unroll
    for (int j = 0; j < 8; ++j)
      *(bf16x8*)(dst + 8*j) = mk8(*(const float4*)(src + 8*j), *(const float4*)(src + 8*j + 4));
  } else {
    int r = tid - 192;
    const float* src = pos_w2 + r*64;
    short* dst = wpos2 + r*72;
    #pragma unroll
    for (int j = 0; j < 8; ++j)
      *(bf16x8*)(dst + 8*j) = mk8(*(const float4*)(src + 8*j), *(const float4*)(src + 8*j + 4));
  }
  // ---- BN fold tables + peB const ----
  if (tid < 64){
    float s = tr_g[tid] * rsqrtf(tr_v[tid] + EPS_BN);
    *(float4*)(trQ + 4*tid) = make_float4(s, tr_bb[tid] - tr_m[tid]*s, pos_b2[tid], 0.f);
    float s2 = pos_g[tid] * rsqrtf(pos_v[tid] + EPS_BN);
    p1T[2*tid] = s2; p1T[2*tid+1] = pos_bb[tid] - pos_m[tid]*s2;
  } else if (tid < 80){
    int c = tid - 64;
    float s = ga_g[c] * rsqrtf(ga_v[c] + EPS_BN);
    gaT[2*c] = s; gaT[2*c+1] = ga_bb[c] - ga_m[c]*s;
  } else if (tid < 96){
    int c = tid - 80;
    float s = at_g[c] * rsqrtf(at_v[c] + EPS_BN);
    atT[2*c] = s; atT[2*c+1] = at_bb[c] - at_m[c]*s;
  } else if (tid < 112){
    int r2 = tid - 96;
    float v = 0.f;
    if (r2 < 8){
      v = pe_b[r2];
      for (int c = 0; c < 64; ++c) v += pe_w[r2*64 + c] * pos_b2[c];
    }
    peBt[r2] = v;
  }
  // ---- peW2 fold: rows 64..71 of wpos2 = pe_w @ pos_w2 ----
  {
    int o = 2*tid, r = o >> 6, j = o & 63;
    float c0 = 0.f, c1 = 0.f;
    for (int c = 0; c < 64; ++c){
      float a = pe_w[r*64 + c];
      c0 += a * pos_w2[c*64 + j];
      c1 += a * pos_w2[c*64 + j + 1];
    }
    *(unsigned*)(wpos2 + (64 + r)*72 + j) = pk2(c0, c1);
  }

  // ---- small weights / consts -> registers ----
  uint2 pw1p[4];    // compressed pos_w1 fragments (elems 0..2 valid, rest 0)
  #pragma unroll
  for (int m2 = 0; m2 < 4; ++m2){
    uint2 t = make_uint2(0u, 0u);
    if (g4 == 0){
      const float* rp = pos_w1 + (16*m2 + l15)*3;
      t.x = pk2(rp[0], rp[1]);
      t.y = pk2(rp[2], 0.f);
    }
    pw1p[m2] = t;
  }
  bf16x8 gaf;
  {
    bf16x8 t = {0,0,0,0,0,0,0,0};
    #pragma unroll
    for (int j = 0; j < 8; ++j){
      int k = 8*g4 + j;
      float v2 = 0.f;
      if (l15 < 8)       { if (k >= 16) v2 = attn_w2[l15*16 + (k-16)]; }
      else if (l15 == 8) { if (k < 16)  v2 = gate_w2[k]; }
      t[j] = f2bf(v2);
    }
    gaf = t;
  }
  const float gb2v = gate_b2[0];

  __syncthreads();   // LDS weights + tables visible

  float lcr[4];      // attn_b2 + peB combined logit const (needs peBt)
  #pragma unroll
  for (int r = 0; r < 4; ++r){
    int row = 4*g4 + r;
    lcr[r] = peBt[row] + ((row < 8) ? attn_b2[row] : 0.f);
  }

  // ---- per-wave constants ----
  const int col0 = 32*wv + l15, col1 = col0 + 16;
  const int lc0 = l15, lc1 = l15 + 16;
  const int lq = l & 7, ld = l >> 3;
  const int colb = 32*wv + 4*lq;
  char*  slice = smem + wv*8704;
  short* h1b   = (short*)slice;            // [32][72]
  short* gab   = (short*)(slice + 4608);   // [32][40]
  const float* xp0 = x + (((long)(b*128 + 8*ld)) << 16) + colb;
  const float* rpb = rel_pos + (((long)(3*b)) << 16);
  float* outb = out + (((long)(b*64)) << 11) + nblk + wv;

  // ---- prologue: prefetch iteration 0 ----
  f32x4 fa[8], fb[8];
  float rc[6] = {0.f,0.f,0.f,0.f,0.f,0.f};
  {
    const long sb0 = (long)nblk * 32;
    #pragma unroll
    for (int j = 0; j < 8; ++j) fa[j] = *(const f32x4*)(xp0 + sb0 + (((long)j) << 16));
    #pragma unroll
    for (int j = 0; j < 8; ++j) fb[j] = *(const f32x4*)(xp0 + sb0 + (((long)(64+j)) << 16));
    if (g4 == 0){
      long sg = sb0 + col0;
      rc[0] = rpb[sg];          rc[1] = rpb[sg + 65536];      rc[2] = rpb[sg + 131072];
      rc[3] = rpb[sg + 16];     rc[4] = rpb[sg + 65536 + 16]; rc[5] = rpb[sg + 131072 + 16];
    }
  }

  for (int it = 0; it < 8; ++it){
    const long sbase = (long)nblk*32 + 128*it;

    // (1) cvt + write staged tile -> own xbuf slice (consumes fa,fb)
    #pragma unroll
    for (int i2 = 0; i2 < 4; ++i2){
      union { bf16x8 v; unsigned u[4]; } ta, tb2;
      ta.u[0] = pk2(fa[0][i2], fa[1][i2]); ta.u[1] = pk2(fa[2][i2], fa[3][i2]);
      ta.u[2] = pk2(fa[4][i2], fa[5][i2]); ta.u[3] = pk2(fa[6][i2], fa[7][i2]);
      *(bf16x8*)(xbuf + (colb+i2)*136 + 8*ld) = ta.v;
      tb2.u[0] = pk2(fb[0][i2], fb[1][i2]); tb2.u[1] = pk2(fb[2][i2], fb[3][i2]);
      tb2.u[2] = pk2(fb[4][i2], fb[5][i2]); tb2.u[3] = pk2(fb[6][i2], fb[7][i2]);
      *(bf16x8*)(xbuf + (colb+i2)*136 + 64 + 8*ld) = tb2.v;
    }

    const long nsb = sbase + ((it < 7) ? 128 : 0);
    // (2) prefetch fa half for next iter (in flight across GEMM)
    #pragma unroll
    for (int j = 0; j < 8; ++j) fa[j] = *(const f32x4*)(xp0 + nsb + (((long)j) << 16));

    // (3) main GEMM: [96x128] @ xtile
    f32x4 acc[6][2];
    #pragma unroll
    for (int m = 0; m < 6; ++m){
      f32x4 z = {0.f,0.f,0.f,0.f};
      acc[m][0] = z; acc[m][1] = z;
    }
    #pragma unroll
    for (int ks = 0; ks < 4; ++ks){
      bf16x8 b0 = *(const bf16x8*)(xbuf + col0*136 + 32*ks + 8*g4);
      bf16x8 b1 = *(const bf16x8*)(xbuf + col1*136 + 32*ks + 8*g4);
      #pragma unroll
      for (int m = 0; m < 6; ++m){
        bf16x8 af = *(const bf16x8*)(wmain + (16*m + l15)*136 + 32*ks + 8*g4);
        acc[m][0] = MFMA16(af, b0, acc[m][0]);
        acc[m][1] = MFMA16(af, b1, acc[m][1]);
      }
    }

    // (4) prefetch fb half for next iter (in flight across epilogue)
    #pragma unroll
    for (int j = 0; j < 8; ++j) fb[j] = *(const f32x4*)(xp0 + nsb + (((long)(64+j)) << 16));

    // (5) pos layer 1 (K padded 3->32) -> h1b ; uses rc of CURRENT iter
    {
      bf16x8 rf0 = {0,0,0,0,0,0,0,0}, rf1 = {0,0,0,0,0,0,0,0};
      if (g4 == 0){
        union { bf16x8 v; unsigned u[4]; } t0, t1;
        t0.u[0] = pk2(rc[0], rc[1]); t0.u[1] = pk2(rc[2], 0.f); t0.u[2] = 0u; t0.u[3] = 0u;
        t1.u[0] = pk2(rc[3], rc[4]); t1.u[1] = pk2(rc[5], 0.f); t1.u[2] = 0u; t1.u[3] = 0u;
        rf0 = t0.v; rf1 = t1.v;
      }
      #pragma unroll
      for (int m2 = 0; m2 < 4; ++m2){
        union { bf16x8 v; unsigned u[4]; } aw;
        aw.u[0] = pw1p[m2].x; aw.u[1] = pw1p[m2].y; aw.u[2] = 0u; aw.u[3] = 0u;
        f32x4 z = {0.f,0.f,0.f,0.f};
        f32x4 d0 = MFMA16(aw.v, rf0, z);
        f32x4 d1 = MFMA16(aw.v, rf1, z);
        int cb2 = 16*m2 + 4*g4;
        float2 t0 = *(const float2*)(p1T + 2*(cb2+0));
        float2 t1 = *(const float2*)(p1T + 2*(cb2+1));
        float2 t2 = *(const float2*)(p1T + 2*(cb2+2));
        float2 t3 = *(const float2*)(p1T + 2*(cb2+3));
        float h0 = lrelu(t0.x*d0[0]+t0.y), h1v = lrelu(t1.x*d0[1]+t1.y);
        float h2 = lrelu(t2.x*d0[2]+t2.y), h3 = lrelu(t3.x*d0[3]+t3.y);
        *(uint2*)(h1b + lc0*72 + cb2) = make_uint2(pk2(h0,h1v), pk2(h2,h3));
        h0 = lrelu(t0.x*d1[0]+t0.y); h1v = lrelu(t1.x*d1[1]+t1.y);
        h2 = lrelu(t2.x*d1[2]+t2.y); h3 = lrelu(t3.x*d1[3]+t3.y);
        *(uint2*)(h1b + lc1*72 + cb2) = make_uint2(pk2(h0,h1v), pk2(h2,h3));
      }
    }
    // (5b) prefetch rel_pos for NEXT iter (after use)
    if (g4 == 0){
      long sg = nsb + col0;
      rc[0] = rpb[sg];          rc[1] = rpb[sg + 65536];      rc[2] = rpb[sg + 131072];
      rc[3] = rpb[sg + 16];     rc[4] = rpb[sg + 65536 + 16]; rc[5] = rpb[sg + 131072 + 16];
    }

    // (6) pos2 + pe-fold: rows 0..63 pos_enc, 64..71 pe logits
    f32x4 pacc[5][2];
    #pragma unroll
    for (int m2 = 0; m2 < 5; ++m2){
      f32x4 z = {0.f,0.f,0.f,0.f};
      pacc[m2][0] = z; pacc[m2][1] = z;
    }
    #pragma unroll
    for (int ks = 0; ks < 2; ++ks){
      bf16x8 h0 = *(const bf16x8*)(h1b + lc0*72 + 32*ks + 8*g4);
      bf16x8 h1v = *(const bf16x8*)(h1b + lc1*72 + 32*ks + 8*g4);
      #pragma unroll
      for (int m2 = 0; m2 < 5; ++m2){
        bf16x8 af = *(const bf16x8*)(wpos2 + (16*m2 + l15)*72 + 32*ks + 8*g4);
        pacc[m2][0] = MFMA16(af, h0, pacc[m2][0]);
        pacc[m2][1] = MFMA16(af, h1v, pacc[m2][1]);
      }
    }

    // (7) trans epilogue: trans_feat = lrelu(BN(conv)) + pos_enc + pos_b2
    #pragma unroll
    for (int m = 0; m < 4; ++m)
      #pragma unroll
      for (int r = 0; r < 4; ++r){
        float4 tq = *(const float4*)(trQ + 4*(16*m + 4*g4 + r));
        acc[m][0][r] = lrelu(tq.x*acc[m][0][r] + tq.y) + pacc[m][0][r] + tq.z;
        acc[m][1][r] = lrelu(tq.x*acc[m][1][r] + tq.y) + pacc[m][1][r] + tq.z;
      }

    // (8) hidden epilogues -> gab (gate_h ch 0..15, attn_h ch 16..31)
    {
      int hc = 4*g4;
      float2 g0p = *(const float2*)(gaT + 2*(hc+0));
      float2 g1p = *(const float2*)(gaT + 2*(hc+1));
      float2 g2p = *(const float2*)(gaT + 2*(hc+2));
      float2 g3p = *(const float2*)(gaT + 2*(hc+3));
      float2 a0p = *(const float2*)(atT + 2*(hc+0));
      float2 a1p = *(const float2*)(atT + 2*(hc+1));
      float2 a2p = *(const float2*)(atT + 2*(hc+2));
      float2 a3p = *(const float2*)(atT + 2*(hc+3));
      #pragma unroll
      for (int ct = 0; ct < 2; ++ct){
        int lc = (ct == 0) ? lc0 : lc1;
        float q0 = lrelu(g0p.x*acc[4][ct][0] + g0p.y), q1 = lrelu(g1p.x*acc[4][ct][1] + g1p.y);
        float q2 = lrelu(g2p.x*acc[4][ct][2] + g2p.y), q3 = lrelu(g3p.x*acc[4][ct][3] + g3p.y);
        *(uint2*)(gab + lc*40 + hc) = make_uint2(pk2(q0,q1), pk2(q2,q3));
        float a0 = lrelu(a0p.x*acc[5][ct][0] + a0p.y), a1 = lrelu(a1p.x*acc[5][ct][1] + a1p.y);
        float a2 = lrelu(a2p.x*acc[5][ct][2] + a2p.y), a3 = lrelu(a3p.x*acc[5][ct][3] + a3p.y);
        *(uint2*)(gab + lc*40 + 16 + hc) = make_uint2(pk2(a0,a1), pk2(a2,a3));
      }
    }

    // (9) gate/attn layer-2 MFMA (rows 0..7 attn, row 8 gate)
    f32x4 gac0 = {0.f,0.f,0.f,0.f}, gac1 = gac0;
    {
      bf16x8 g0 = *(const bf16x8*)(gab + lc0*40 + 8*g4);
      bf16x8 g1 = *(const bf16x8*)(gab + lc1*40 + 8*g4);
      gac0 = MFMA16(gaf, g0, gac0);
      gac1 = MFMA16(gaf, g1, gac1);
    }

    // (10) gate, logits, softmax over k (DPP reduce), direct stores
    float gv0 = __shfl(gac0[0], 32 + l15, 64);
    float gv1 = __shfl(gac1[0], 32 + l15, 64);
    float gm0 = 1.f/(1.f + __expf(-(gv0 + gb2v)));
    float gm1 = 1.f/(1.f + __expf(-(gv1 + gb2v)));
    float lg0 = __logf(gm0 + 1e-6f), lg1 = __logf(gm1 + 1e-6f);

    float wg0[4], wg1[4];
    #pragma unroll
    for (int r = 0; r < 4; ++r){
      float t0 = gac0[r] + pacc[4][0][r] + lcr[r] + lg0;
      float t1 = gac1[r] + pacc[4][1][r] + lcr[r] + lg1;
      float mx = rmax16(fmaxf(t0, t1));
      float e0 = __expf(t0 - mx), e1 = __expf(t1 - mx);
      float inv = 1.f / rsum16(e0 + e1);
      wg0[r] = e0 * inv; wg1[r] = e1 * inv;
    }
    float wf0[8], wf1[8];
    #pragma unroll
    for (int gg = 0; gg < 8; ++gg){
      int src = 16*(gg >> 2) + l15;
      wf0[gg] = __shfl(wg0[gg & 3], src, 64);
      wf1[gg] = __shfl(wg1[gg & 3], src, 64);
    }
    const bool hi = (g4 >= 2);
    #pragma unroll
    for (int m = 0; m < 4; ++m){
      float w0 = hi ? wf0[2*m+1] : wf0[2*m];
      float w1 = hi ? wf1[2*m+1] : wf1[2*m];
      #pragma unroll
      for (int r = 0; r < 4; ++r){
        float sA = rsum16(acc[m][0][r]*w0 + acc[m][1][r]*w1);
        float sM = rmax16(fmaxf(acc[m][0][r]*gm0, acc[m][1][r]*gm1));
        if (l15 == 0)
          outb[(((long)(16*m + 4*g4 + r)) << 11) + 4*it] = sA + sM;
      }
    }
  }
}

extern "C" void kernel_launch(void* const* d_in, const int* in_sizes, int n_in,
                              void* d_out, int out_size, void* d_ws, size_t ws_size,
                              hipStream_t stream){
  (void)in_sizes; (void)n_in; (void)out_size; (void)d_ws; (void)ws_size;
  gsl_fused<<<dim3(512), dim3(256), 0, stream>>>(
    (const float*)d_in[0],  (const float*)d_in[1],  (const float*)d_in[2],
    (const float*)d_in[3],  (const float*)d_in[4],  (const float*)d_in[5],
    (const float*)d_in[6],  (const float*)d_in[7],  (const float*)d_in[8],
    (const float*)d_in[9],  (const float*)d_in[10], (const float*)d_in[11],
    (const float*)d_in[12], (const float*)d_in[13], (const float*)d_in[14],
    (const float*)d_in[15], (const float*)d_in[16], (const float*)d_in[17],
    (const float*)d_in[18], (const float*)d_in[19], (const float*)d_in[20],
    (const float*)d_in[21], (const float*)d_in[22], (const float*)d_in[23],
    (const float*)d_in[24], (const float*)d_in[25], (const float*)d_in[26],
    (const float*)d_in[27], (const float*)d_in[28], (const float*)d_in[29],
    (float*)d_out);
}

// Round 7
// 75.628 us; speedup vs baseline: 1.9619x; 1.9619x over previous
//
#include <hip/hip_runtime.h>

// Grouped_Soft_GSL_Block_PE fused kernel for MI355X (gfx950).
// B=8, IC2=128, N=2048, K=32, C=64, G=8, CPG=8, hidden=16.
// R7: 512 blocks, 256 thr / 4 waves; block owns 32 n, 8 iterations of
// (4 n)-tiles; wave wv owns n = nblk + 4*it + wv. Zero barriers in loop.
// Changes vs R6: pacc[0..3] eliminated (32 AGPRs) by applying the trans
// BN+lrelu+pos_b2 epilogue BEFORE pos2, then accumulating the pos2 MFMAs
// directly into acc[0..3] (MFMA C-in==C-out). Total reg demand ~232 <= 256
// -> 2 waves/SIMD WITHOUT spill (R6 spilled 43MB meeting the same bound).

typedef __attribute__((ext_vector_type(8))) short bf16x8;
typedef __attribute__((ext_vector_type(4))) float f32x4;

#define EPS_BN 1e-5f

__device__ __forceinline__ unsigned pk2(float a, float b){
  unsigned ua = __float_as_uint(a) + 0x8000u;
  unsigned ub = __float_as_uint(b) + 0x8000u;
  return __builtin_amdgcn_perm(ub, ua, 0x07060302);
}
__device__ __forceinline__ short f2bf(float a){
  unsigned u = __float_as_uint(a);
  u += 0x7FFFu + ((u >> 16) & 1u);
  return (short)(u >> 16);
}
__device__ __forceinline__ bf16x8 mk8(float4 a, float4 b){
  union { bf16x8 v; unsigned u[4]; } t;
  t.u[0] = pk2(a.x, a.y); t.u[1] = pk2(a.z, a.w);
  t.u[2] = pk2(b.x, b.y); t.u[3] = pk2(b.z, b.w);
  return t.v;
}
__device__ __forceinline__ float lrelu(float v){ return fmaxf(v, 0.2f*v); }

// DPP row_ror reductions over the 16-lane row (l15 = k dimension)
template<int N>
__device__ __forceinline__ float ror16(float x){
  return __int_as_float(__builtin_amdgcn_mov_dpp(__float_as_int(x), 0x120+N, 0xF, 0xF, false));
}
__device__ __forceinline__ float rsum16(float v){
  v += ror16<1>(v); v += ror16<2>(v); v += ror16<4>(v); v += ror16<8>(v); return v;
}
__device__ __forceinline__ float rmax16(float v){
  v = fmaxf(v, ror16<1>(v)); v = fmaxf(v, ror16<2>(v));
  v = fmaxf(v, ror16<4>(v)); v = fmaxf(v, ror16<8>(v)); return v;
}

#define MFMA16(a,b,c) __builtin_amdgcn_mfma_f32_16x16x32_bf16((a),(b),(c),0,0,0)

__global__ __launch_bounds__(256, 2)
void gsl_fused(const float* __restrict__ x,       const float* __restrict__ rel_pos,
               const float* __restrict__ pos_w1,  const float* __restrict__ pos_g,
               const float* __restrict__ pos_bb,  const float* __restrict__ pos_m,
               const float* __restrict__ pos_v,   const float* __restrict__ pos_w2,
               const float* __restrict__ pos_b2,  const float* __restrict__ pe_w,
               const float* __restrict__ pe_b,    const float* __restrict__ trans_w,
               const float* __restrict__ tr_g,    const float* __restrict__ tr_bb,
               const float* __restrict__ tr_m,    const float* __restrict__ tr_v,
               const float* __restrict__ gate_w1, const float* __restrict__ ga_g,
               const float* __restrict__ ga_bb,   const float* __restrict__ ga_m,
               const float* __restrict__ ga_v,    const float* __restrict__ gate_w2,
               const float* __restrict__ gate_b2, const float* __restrict__ attn_w1,
               const float* __restrict__ at_g,    const float* __restrict__ at_bb,
               const float* __restrict__ at_m,    const float* __restrict__ at_v,
               const float* __restrict__ attn_w2, const float* __restrict__ attn_b2,
               float* __restrict__ out)
{
  // LDS map (73216 B, 2 blocks/CU):
  // [0,34816)      xbuf [128 cols][136] bf16; wave slice 8704B at wv*8704,
  //                aliased post-GEMM per wave: h1b [32][72] @0, gab [32][40] @4608
  // [34816,60928)  wmain [96][136] bf16 (trans 0..63, gate 64..79, attn 80..95)
  // [60928,71296)  wpos2 [72][72] bf16 (rows 0..63 pos_w2; 64..71 peW2 fold)
  // [71296,73152)  tabs f32: trQ[256] (s,b,pos_b2,0 quads) p1T[128] gaT[32]
  //                atT[32] peBt[16]
  __shared__ __align__(16) char smem[73216];
  short* xbuf  = (short*)smem;
  short* wmain = (short*)(smem + 34816);
  short* wpos2 = (short*)(smem + 60928);
  float* trQ  = (float*)(smem + 71296);
  float* p1T  = (float*)(smem + 72320);
  float* gaT  = (float*)(smem + 72832);
  float* atT  = (float*)(smem + 72960);
  float* peBt = (float*)(smem + 73088);

  const int tid = threadIdx.x;
  const int wv  = tid >> 6;
  const int l   = tid & 63;
  const int l15 = l & 15, g4 = l >> 4;
  const int bid = blockIdx.x;
  const int b    = bid >> 6;
  const int nblk = (bid & 63) << 5;

  // ---- stage weights -> LDS bf16 ----
  if (tid < 192){
    int r = tid >> 1, c0 = (tid & 1) * 64;
    const float* src = (r < 64) ? (trans_w + r*128)
                     : (r < 80) ? (gate_w1 + (r-64)*128)
                                : (attn_w1 + (r-80)*128);
    src += c0;
    short* dst = wmain + r*136 + c0;
    #pragma unroll
    for (int j = 0; j < 8; ++j)
      *(bf16x8*)(dst + 8*j) = mk8(*(const float4*)(src + 8*j), *(const float4*)(src + 8*j + 4));
  } else {
    int r = tid - 192;
    const float* src = pos_w2 + r*64;
    short* dst = wpos2 + r*72;
    #pragma unroll
    for (int j = 0; j < 8; ++j)
      *(bf16x8*)(dst + 8*j) = mk8(*(const float4*)(src + 8*j), *(const float4*)(src + 8*j + 4));
  }
  // ---- BN fold tables + peB const ----
  if (tid < 64){
    float s = tr_g[tid] * rsqrtf(tr_v[tid] + EPS_BN);
    *(float4*)(trQ + 4*tid) = make_float4(s, tr_bb[tid] - tr_m[tid]*s, pos_b2[tid], 0.f);
    float s2 = pos_g[tid] * rsqrtf(pos_v[tid] + EPS_BN);
    p1T[2*tid] = s2; p1T[2*tid+1] = pos_bb[tid] - pos_m[tid]*s2;
  } else if (tid < 80){
    int c = tid - 64;
    float s = ga_g[c] * rsqrtf(ga_v[c] + EPS_BN);
    gaT[2*c] = s; gaT[2*c+1] = ga_bb[c] - ga_m[c]*s;
  } else if (tid < 96){
    int c = tid - 80;
    float s = at_g[c] * rsqrtf(at_v[c] + EPS_BN);
    atT[2*c] = s; atT[2*c+1] = at_bb[c] - at_m[c]*s;
  } else if (tid < 112){
    int r2 = tid - 96;
    float v = 0.f;
    if (r2 < 8){
      v = pe_b[r2];
      for (int c = 0; c < 64; ++c) v += pe_w[r2*64 + c] * pos_b2[c];
    }
    peBt[r2] = v;
  }
  // ---- peW2 fold: rows 64..71 of wpos2 = pe_w @ pos_w2 ----
  {
    int o = 2*tid, r = o >> 6, j = o & 63;
    float c0 = 0.f, c1 = 0.f;
    for (int c = 0; c < 64; ++c){
      float a = pe_w[r*64 + c];
      c0 += a * pos_w2[c*64 + j];
      c1 += a * pos_w2[c*64 + j + 1];
    }
    *(unsigned*)(wpos2 + (64 + r)*72 + j) = pk2(c0, c1);
  }

  // ---- small weights / consts -> registers ----
  uint2 pw1p[4];
  #pragma unroll
  for (int m2 = 0; m2 < 4; ++m2){
    uint2 t = make_uint2(0u, 0u);
    if (g4 == 0){
      const float* rp = pos_w1 + (16*m2 + l15)*3;
      t.x = pk2(rp[0], rp[1]);
      t.y = pk2(rp[2], 0.f);
    }
    pw1p[m2] = t;
  }
  bf16x8 gaf;
  {
    bf16x8 t = {0,0,0,0,0,0,0,0};
    #pragma unroll
    for (int j = 0; j < 8; ++j){
      int k = 8*g4 + j;
      float v2 = 0.f;
      if (l15 < 8)       { if (k >= 16) v2 = attn_w2[l15*16 + (k-16)]; }
      else if (l15 == 8) { if (k < 16)  v2 = gate_w2[k]; }
      t[j] = f2bf(v2);
    }
    gaf = t;
  }
  const float gb2v = gate_b2[0];

  __syncthreads();   // LDS weights + tables visible

  float lcr[4];
  #pragma unroll
  for (int r = 0; r < 4; ++r){
    int row = 4*g4 + r;
    lcr[r] = peBt[row] + ((row < 8) ? attn_b2[row] : 0.f);
  }

  // ---- per-wave constants ----
  const int col0 = 32*wv + l15, col1 = col0 + 16;
  const int lc0 = l15, lc1 = l15 + 16;
  const int lq = l & 7, ld = l >> 3;
  const int colb = 32*wv + 4*lq;
  char*  slice = smem + wv*8704;
  short* h1b   = (short*)slice;            // [32][72]
  short* gab   = (short*)(slice + 4608);   // [32][40]
  const float* xp0 = x + (((long)(b*128 + 8*ld)) << 16) + colb;
  const float* rpb = rel_pos + (((long)(3*b)) << 16);
  float* outb = out + (((long)(b*64)) << 11) + nblk + wv;

  // ---- prologue: prefetch iteration 0 ----
  f32x4 fa[8], fb[8];
  float rc[6] = {0.f,0.f,0.f,0.f,0.f,0.f};
  {
    const long sb0 = (long)nblk * 32;
    #pragma unroll
    for (int j = 0; j < 8; ++j) fa[j] = *(const f32x4*)(xp0 + sb0 + (((long)j) << 16));
    #pragma unroll
    for (int j = 0; j < 8; ++j) fb[j] = *(const f32x4*)(xp0 + sb0 + (((long)(64+j)) << 16));
    if (g4 == 0){
      long sg = sb0 + col0;
      rc[0] = rpb[sg];          rc[1] = rpb[sg + 65536];      rc[2] = rpb[sg + 131072];
      rc[3] = rpb[sg + 16];     rc[4] = rpb[sg + 65536 + 16]; rc[5] = rpb[sg + 131072 + 16];
    }
  }

  for (int it = 0; it < 8; ++it){
    const long sbase = (long)nblk*32 + 128*it;

    // (1) cvt + write staged tile -> own xbuf slice (consumes fa,fb)
    #pragma unroll
    for (int i2 = 0; i2 < 4; ++i2){
      union { bf16x8 v; unsigned u[4]; } ta, tb2;
      ta.u[0] = pk2(fa[0][i2], fa[1][i2]); ta.u[1] = pk2(fa[2][i2], fa[3][i2]);
      ta.u[2] = pk2(fa[4][i2], fa[5][i2]); ta.u[3] = pk2(fa[6][i2], fa[7][i2]);
      *(bf16x8*)(xbuf + (colb+i2)*136 + 8*ld) = ta.v;
      tb2.u[0] = pk2(fb[0][i2], fb[1][i2]); tb2.u[1] = pk2(fb[2][i2], fb[3][i2]);
      tb2.u[2] = pk2(fb[4][i2], fb[5][i2]); tb2.u[3] = pk2(fb[6][i2], fb[7][i2]);
      *(bf16x8*)(xbuf + (colb+i2)*136 + 64 + 8*ld) = tb2.v;
    }

    const long nsb = sbase + ((it < 7) ? 128 : 0);
    // (2) prefetch fa half for next iter (in flight across GEMM)
    #pragma unroll
    for (int j = 0; j < 8; ++j) fa[j] = *(const f32x4*)(xp0 + nsb + (((long)j) << 16));

    // (3) main GEMM: [96x128] @ xtile
    f32x4 acc[6][2];
    #pragma unroll
    for (int m = 0; m < 6; ++m){
      f32x4 z = {0.f,0.f,0.f,0.f};
      acc[m][0] = z; acc[m][1] = z;
    }
    #pragma unroll
    for (int ks = 0; ks < 4; ++ks){
      bf16x8 b0 = *(const bf16x8*)(xbuf + col0*136 + 32*ks + 8*g4);
      bf16x8 b1 = *(const bf16x8*)(xbuf + col1*136 + 32*ks + 8*g4);
      #pragma unroll
      for (int m = 0; m < 6; ++m){
        bf16x8 af = *(const bf16x8*)(wmain + (16*m + l15)*136 + 32*ks + 8*g4);
        acc[m][0] = MFMA16(af, b0, acc[m][0]);
        acc[m][1] = MFMA16(af, b1, acc[m][1]);
      }
    }

    // (4) prefetch fb half for next iter (in flight across epilogue)
    #pragma unroll
    for (int j = 0; j < 8; ++j) fb[j] = *(const f32x4*)(xp0 + nsb + (((long)(64+j)) << 16));

    // (5) pos layer 1 (K padded 3->32) -> h1b ; uses rc of CURRENT iter
    {
      bf16x8 rf0 = {0,0,0,0,0,0,0,0}, rf1 = {0,0,0,0,0,0,0,0};
      if (g4 == 0){
        union { bf16x8 v; unsigned u[4]; } t0, t1;
        t0.u[0] = pk2(rc[0], rc[1]); t0.u[1] = pk2(rc[2], 0.f); t0.u[2] = 0u; t0.u[3] = 0u;
        t1.u[0] = pk2(rc[3], rc[4]); t1.u[1] = pk2(rc[5], 0.f); t1.u[2] = 0u; t1.u[3] = 0u;
        rf0 = t0.v; rf1 = t1.v;
      }
      #pragma unroll
      for (int m2 = 0; m2 < 4; ++m2){
        union { bf16x8 v; unsigned u[4]; } aw;
        aw.u[0] = pw1p[m2].x; aw.u[1] = pw1p[m2].y; aw.u[2] = 0u; aw.u[3] = 0u;
        f32x4 z = {0.f,0.f,0.f,0.f};
        f32x4 d0 = MFMA16(aw.v, rf0, z);
        f32x4 d1 = MFMA16(aw.v, rf1, z);
        int cb2 = 16*m2 + 4*g4;
        float2 t0 = *(const float2*)(p1T + 2*(cb2+0));
        float2 t1 = *(const float2*)(p1T + 2*(cb2+1));
        float2 t2 = *(const float2*)(p1T + 2*(cb2+2));
        float2 t3 = *(const float2*)(p1T + 2*(cb2+3));
        float h0 = lrelu(t0.x*d0[0]+t0.y), h1v = lrelu(t1.x*d0[1]+t1.y);
        float h2 = lrelu(t2.x*d0[2]+t2.y), h3 = lrelu(t3.x*d0[3]+t3.y);
        *(uint2*)(h1b + lc0*72 + cb2) = make_uint2(pk2(h0,h1v), pk2(h2,h3));
        h0 = lrelu(t0.x*d1[0]+t0.y); h1v = lrelu(t1.x*d1[1]+t1.y);
        h2 = lrelu(t2.x*d1[2]+t2.y); h3 = lrelu(t3.x*d1[3]+t3.y);
        *(uint2*)(h1b + lc1*72 + cb2) = make_uint2(pk2(h0,h1v), pk2(h2,h3));
      }
    }
    // (5b) prefetch rel_pos for NEXT iter (after use)
    if (g4 == 0){
      long sg = nsb + col0;
      rc[0] = rpb[sg];          rc[1] = rpb[sg + 65536];      rc[2] = rpb[sg + 131072];
      rc[3] = rpb[sg + 16];     rc[4] = rpb[sg + 65536 + 16]; rc[5] = rpb[sg + 131072 + 16];
    }

    // (6) trans epilogue FIRST: acc[0..3] = lrelu(BN(conv)) + pos_b2
    //     (frees pos2 to accumulate in place -> pacc[0..3] eliminated)
    #pragma unroll
    for (int m = 0; m < 4; ++m)
      #pragma unroll
      for (int r = 0; r < 4; ++r){
        float4 tq = *(const float4*)(trQ + 4*(16*m + 4*g4 + r));
        acc[m][0][r] = lrelu(tq.x*acc[m][0][r] + tq.y) + tq.z;
        acc[m][1][r] = lrelu(tq.x*acc[m][1][r] + tq.y) + tq.z;
      }

    // (7) pos2 MFMAs accumulate INTO acc[0..3]; pe-fold rows -> pac4
    f32x4 pac4[2];
    {
      f32x4 z = {0.f,0.f,0.f,0.f};
      pac4[0] = z; pac4[1] = z;
    }
    #pragma unroll
    for (int ks = 0; ks < 2; ++ks){
      bf16x8 h0 = *(const bf16x8*)(h1b + lc0*72 + 32*ks + 8*g4);
      bf16x8 h1v = *(const bf16x8*)(h1b + lc1*72 + 32*ks + 8*g4);
      #pragma unroll
      for (int m2 = 0; m2 < 4; ++m2){
        bf16x8 af = *(const bf16x8*)(wpos2 + (16*m2 + l15)*72 + 32*ks + 8*g4);
        acc[m2][0] = MFMA16(af, h0, acc[m2][0]);
        acc[m2][1] = MFMA16(af, h1v, acc[m2][1]);
      }
      bf16x8 af4 = *(const bf16x8*)(wpos2 + (64 + l15)*72 + 32*ks + 8*g4);
      pac4[0] = MFMA16(af4, h0, pac4[0]);
      pac4[1] = MFMA16(af4, h1v, pac4[1]);
    }

    // (8) hidden epilogues -> gab (gate_h ch 0..15, attn_h ch 16..31)
    {
      int hc = 4*g4;
      float2 g0p = *(const float2*)(gaT + 2*(hc+0));
      float2 g1p = *(const float2*)(gaT + 2*(hc+1));
      float2 g2p = *(const float2*)(gaT + 2*(hc+2));
      float2 g3p = *(const float2*)(gaT + 2*(hc+3));
      float2 a0p = *(const float2*)(atT + 2*(hc+0));
      float2 a1p = *(const float2*)(atT + 2*(hc+1));
      float2 a2p = *(const float2*)(atT + 2*(hc+2));
      float2 a3p = *(const float2*)(atT + 2*(hc+3));
      #pragma unroll
      for (int ct = 0; ct < 2; ++ct){
        int lc = (ct == 0) ? lc0 : lc1;
        float q0 = lrelu(g0p.x*acc[4][ct][0] + g0p.y), q1 = lrelu(g1p.x*acc[4][ct][1] + g1p.y);
        float q2 = lrelu(g2p.x*acc[4][ct][2] + g2p.y), q3 = lrelu(g3p.x*acc[4][ct][3] + g3p.y);
        *(uint2*)(gab + lc*40 + hc) = make_uint2(pk2(q0,q1), pk2(q2,q3));
        float a0 = lrelu(a0p.x*acc[5][ct][0] + a0p.y), a1 = lrelu(a1p.x*acc[5][ct][1] + a1p.y);
        float a2 = lrelu(a2p.x*acc[5][ct][2] + a2p.y), a3 = lrelu(a3p.x*acc[5][ct][3] + a3p.y);
        *(uint2*)(gab + lc*40 + 16 + hc) = make_uint2(pk2(a0,a1), pk2(a2,a3));
      }
    }

    // (9) gate/attn layer-2 MFMA (rows 0..7 attn, row 8 gate)
    f32x4 gac0 = {0.f,0.f,0.f,0.f}, gac1 = gac0;
    {
      bf16x8 g0 = *(const bf16x8*)(gab + lc0*40 + 8*g4);
      bf16x8 g1 = *(const bf16x8*)(gab + lc1*40 + 8*g4);
      gac0 = MFMA16(gaf, g0, gac0);
      gac1 = MFMA16(gaf, g1, gac1);
    }

    // (10) gate, logits, softmax over k (DPP reduce), direct stores
    float gv0 = __shfl(gac0[0], 32 + l15, 64);
    float gv1 = __shfl(gac1[0], 32 + l15, 64);
    float gm0 = 1.f/(1.f + __expf(-(gv0 + gb2v)));
    float gm1 = 1.f/(1.f + __expf(-(gv1 + gb2v)));
    float lg0 = __logf(gm0 + 1e-6f), lg1 = __logf(gm1 + 1e-6f);

    float wg0[4], wg1[4];
    #pragma unroll
    for (int r = 0; r < 4; ++r){
      float t0 = gac0[r] + pac4[0][r] + lcr[r] + lg0;
      float t1 = gac1[r] + pac4[1][r] + lcr[r] + lg1;
      float mx = rmax16(fmaxf(t0, t1));
      float e0 = __expf(t0 - mx), e1 = __expf(t1 - mx);
      float inv = 1.f / rsum16(e0 + e1);
      wg0[r] = e0 * inv; wg1[r] = e1 * inv;
    }
    float wf0[8], wf1[8];
    #pragma unroll
    for (int gg = 0; gg < 8; ++gg){
      int src = 16*(gg >> 2) + l15;
      wf0[gg] = __shfl(wg0[gg & 3], src, 64);
      wf1[gg] = __shfl(wg1[gg & 3], src, 64);
    }
    const bool hi = (g4 >= 2);
    #pragma unroll
    for (int m = 0; m < 4; ++m){
      float w0 = hi ? wf0[2*m+1] : wf0[2*m];
      float w1 = hi ? wf1[2*m+1] : wf1[2*m];
      #pragma unroll
      for (int r = 0; r < 4; ++r){
        float sA = rsum16(acc[m][0][r]*w0 + acc[m][1][r]*w1);
        float sM = rmax16(fmaxf(acc[m][0][r]*gm0, acc[m][1][r]*gm1));
        if (l15 == 0)
          outb[(((long)(16*m + 4*g4 + r)) << 11) + 4*it] = sA + sM;
      }
    }
  }
}

extern "C" void kernel_launch(void* const* d_in, const int* in_sizes, int n_in,
                              void* d_out, int out_size, void* d_ws, size_t ws_size,
                              hipStream_t stream){
  (void)in_sizes; (void)n_in; (void)out_size; (void)d_ws; (void)ws_size;
  gsl_fused<<<dim3(512), dim3(256), 0, stream>>>(
    (const float*)d_in[0],  (const float*)d_in[1],  (const float*)d_in[2],
    (const float*)d_in[3],  (const float*)d_in[4],  (const float*)d_in[5],
    (const float*)d_in[6],  (const float*)d_in[7],  (const float*)d_in[8],
    (const float*)d_in[9],  (const float*)d_in[10], (const float*)d_in[11],
    (const float*)d_in[12], (const float*)d_in[13], (const float*)d_in[14],
    (const float*)d_in[15], (const float*)d_in[16], (const float*)d_in[17],
    (const float*)d_in[18], (const float*)d_in[19], (const float*)d_in[20],
    (const float*)d_in[21], (const float*)d_in[22], (const float*)d_in[23],
    (const float*)d_in[24], (const float*)d_in[25], (const float*)d_in[26],
    (const float*)d_in[27], (const float*)d_in[28], (const float*)d_in[29],
    (float*)d_out);
}